// Round 8
// baseline (75.658 us; speedup 1.0000x reference)
//
#include <hip/hip_runtime.h>
#include <math.h>

// Kuramoto fp8-MFMA, round 8: R6's exact step body (measured best: interleaved
// 4-accumulator-chain GEMM, dep distance 4 >= MFMA latency) with R7's single
// confirmed win folded in: K->fp8 conversion in the main prologue (no pack_k
// dispatch). R7's t-major body (dep distance 2) regressed ~5us -> reverted.
//
// GEMM (transposed): G^T = K . S^T; A = K fp8 (VGPR-resident frags), B = staged
// sin/cos fp8. D[row=4q+r -> osc-in-tile][col=l15 -> batch].
// Staging unit u (16B) = [S(8 osc)|C(8 osc)], phys = u ^ l15 swizzle: one
// ds_read_b128 -> long2 {Bs,Bc} used directly as MFMA B-operands (no repack).
// Rotation update: (sin,cos) advanced by small-angle poly (|d|<=0.06, err ~6e-9);
// zero transcendentals in the loop. One barrier/step, double-buffered staging.
// Layouts HW-verified by R2-R7 passing. absmax floor = 1 bf16 ulp (0.015625).

typedef __attribute__((ext_vector_type(4))) float f32x4;
typedef __attribute__((ext_vector_type(2))) long long2_t;

constexpr int N       = 256;
constexpr int RB      = 16;     // batch rows per block -> 64 blocks (structural cap)
constexpr int STEPS   = 10;
constexpr int WAVES   = 8;
constexpr int THREADS = WAVES * 64;
constexpr float DT    = 0.1f;
constexpr float TWO_PI     = 6.28318530717958648f;
constexpr float INV_TWO_PI = 0.15915494309189535f;

__global__ __launch_bounds__(THREADS, 2)
void kuramoto_r8(const float* __restrict__ theta0,
                 const float* __restrict__ Kmat,
                 const float* __restrict__ omega,
                 const float* __restrict__ kglob,
                 float* __restrict__ theta_out,
                 float* __restrict__ coh_out)
{
    // [buf][row l15 * 512B]; 32 units/row of 16B = [S(8)|C(8)]; phys = u ^ l15.
    __shared__ __align__(16) unsigned char SC[2][RB * 512];
    __shared__ float redS[RB][WAVES], redC[RB][WAVES];

    const int tid  = threadIdx.x;
    const int wv   = tid >> 6;      // wave -> osc slab [32wv, 32wv+32), tiles 2wv, 2wv+1
    const int lane = tid & 63;
    const int q    = lane >> 4;
    const int l15  = lane & 15;     // batch-in-block (B-frag n / D col)
    const int b0   = blockIdx.x * RB;

    const float kgn = kglob[0] * (1.0f / 256.0f);

    // ---- K -> fp8 A-frags in-prologue (no pre-dispatch): kf[t][c] ----
    long kf[2][8];
#pragma unroll
    for (int t = 0; t < 2; ++t) {
        const float* kr = Kmat + (size_t)(16 * (2 * wv + t) + l15) * N + 8 * q;
#pragma unroll
        for (int c = 0; c < 8; ++c) {
            float4 lo = *(const float4*)(kr + 32 * c);
            float4 hi = *(const float4*)(kr + 32 * c + 4);
            int w0 = __builtin_amdgcn_cvt_pk_fp8_f32(lo.x, lo.y, 0, false);
            w0     = __builtin_amdgcn_cvt_pk_fp8_f32(lo.z, lo.w, w0, true);
            int w1 = __builtin_amdgcn_cvt_pk_fp8_f32(hi.x, hi.y, 0, false);
            w1     = __builtin_amdgcn_cvt_pk_fp8_f32(hi.z, hi.w, w1, true);
            kf[t][c] = (long)(unsigned)w0 | ((long)w1 << 32);
        }
    }

    // ---- rotation state: 8 osc/thread (t=0,1; r=0..3 at osc 32wv+16t+4q+r) ----
    float th[8], om[8], sn[8], cs[8];
#pragma unroll
    for (int t = 0; t < 2; ++t) {
        const int ob = 32 * wv + 16 * t + 4 * q;
        float4 t4 = *(const float4*)(theta0 + (size_t)(b0 + l15) * N + ob);
        float4 o4 = *(const float4*)(omega + ob);
        th[4*t+0] = t4.x; th[4*t+1] = t4.y; th[4*t+2] = t4.z; th[4*t+3] = t4.w;
        om[4*t+0] = o4.x; om[4*t+1] = o4.y; om[4*t+2] = o4.z; om[4*t+3] = o4.w;
    }
#pragma unroll
    for (int k = 0; k < 8; ++k)
        __sincosf(th[k], &sn[k], &cs[k]);

    const int so = 4 * (q & 1);          // dword slot within unit half
    const int g0 = 4 * wv + (q >> 1);    // staging unit of tile t=0 (t adds 2)

    for (int s = 0; s < STEPS; ++s) {
        unsigned char* rowp = &SC[s & 1][l15 * 512];
        // ---- stage: pack 4 osc of S and C per tile, two b32 writes ----
#pragma unroll
        for (int t = 0; t < 2; ++t) {
            int spk = __builtin_amdgcn_cvt_pk_fp8_f32(sn[4*t+0], sn[4*t+1], 0, false);
            spk     = __builtin_amdgcn_cvt_pk_fp8_f32(sn[4*t+2], sn[4*t+3], spk, true);
            int cpk = __builtin_amdgcn_cvt_pk_fp8_f32(cs[4*t+0], cs[4*t+1], 0, false);
            cpk     = __builtin_amdgcn_cvt_pk_fp8_f32(cs[4*t+2], cs[4*t+3], cpk, true);
            const int base = (((g0 + 2 * t) ^ l15) << 4);
            *(int*)(rowp + base + so)     = spk;   // S half
            *(int*)(rowp + base + 8 + so) = cpk;   // C half
        }
        __syncthreads();   // single barrier/step; double buffer covers WAR

        // ---- GEMMs: one b128 -> {Bs,Bc}, 4 interleaved acc chains (dep dist 4) ----
        f32x4 aS[2], aC[2];
        aS[0] = (f32x4){0.f,0.f,0.f,0.f}; aS[1] = (f32x4){0.f,0.f,0.f,0.f};
        aC[0] = (f32x4){0.f,0.f,0.f,0.f}; aC[1] = (f32x4){0.f,0.f,0.f,0.f};
#pragma unroll
        for (int c = 0; c < 8; ++c) {
            long2_t v = *(const long2_t*)(rowp + ((((4 * c + q) ^ l15)) << 4));
            aS[0] = __builtin_amdgcn_mfma_f32_16x16x32_fp8_fp8(kf[0][c], v.x, aS[0], 0, 0, 0);
            aC[0] = __builtin_amdgcn_mfma_f32_16x16x32_fp8_fp8(kf[0][c], v.y, aC[0], 0, 0, 0);
            aS[1] = __builtin_amdgcn_mfma_f32_16x16x32_fp8_fp8(kf[1][c], v.x, aS[1], 0, 0, 0);
            aC[1] = __builtin_amdgcn_mfma_f32_16x16x32_fp8_fp8(kf[1][c], v.y, aC[1], 0, 0, 0);
        }

        // ---- rotation update (no transcendentals) ----
#pragma unroll
        for (int t = 0; t < 2; ++t)
#pragma unroll
            for (int r = 0; r < 4; ++r) {
                const int k = 4 * t + r;
                float coup = cs[k] * aS[t][r] - sn[k] * aC[t][r];
                float d  = DT * fmaf(kgn, coup, om[k]);
                float d2 = d * d;
                float sd = d * fmaf(d2, -1.0f / 6.0f, 1.0f);              // sin(d)
                float cd = fmaf(d2, fmaf(d2, 1.0f / 24.0f, -0.5f), 1.0f); // cos(d)
                float s2 = fmaf(sn[k], cd,  cs[k] * sd);
                float c2 = fmaf(cs[k], cd, -sn[k] * sd);
                sn[k] = s2; cs[k] = c2; th[k] += d;
            }
    }

    // ---- epilogue: wrap, float4 stores, coherence from live (s,c) ----
    float ps = 0.f, pc = 0.f;
#pragma unroll
    for (int t = 0; t < 2; ++t) {
        const int ob = 32 * wv + 16 * t + 4 * q;
        float4 outv;
        outv.x = fmaf(-TWO_PI, rintf(th[4*t+0] * INV_TWO_PI), th[4*t+0]);
        outv.y = fmaf(-TWO_PI, rintf(th[4*t+1] * INV_TWO_PI), th[4*t+1]);
        outv.z = fmaf(-TWO_PI, rintf(th[4*t+2] * INV_TWO_PI), th[4*t+2]);
        outv.w = fmaf(-TWO_PI, rintf(th[4*t+3] * INV_TWO_PI), th[4*t+3]);
        *(float4*)(theta_out + (size_t)(b0 + l15) * N + ob) = outv;
#pragma unroll
        for (int r = 0; r < 4; ++r) { ps += sn[4*t+r]; pc += cs[4*t+r]; }
    }
    ps += __shfl_xor(ps, 16, 64);  pc += __shfl_xor(pc, 16, 64);
    ps += __shfl_xor(ps, 32, 64);  pc += __shfl_xor(pc, 32, 64);
    if (q == 0) { redS[l15][wv] = ps; redC[l15][wv] = pc; }
    __syncthreads();
    if (tid < RB) {
        float S = 0.f, C = 0.f;
#pragma unroll
        for (int k = 0; k < WAVES; ++k) { S += redS[tid][k]; C += redC[tid][k]; }
        float sm = S * (1.0f / 256.0f);
        float cm = C * (1.0f / 256.0f);
        coh_out[b0 + tid] = sqrtf(sm * sm + cm * cm);
    }
}

extern "C" void kernel_launch(void* const* d_in, const int* in_sizes, int n_in,
                              void* d_out, int out_size, void* d_ws, size_t ws_size,
                              hipStream_t stream) {
    const float* theta0 = (const float*)d_in[0];
    const float* Kmat   = (const float*)d_in[1];
    const float* omega  = (const float*)d_in[2];
    const float* kglob  = (const float*)d_in[3];

    float* theta_out = (float*)d_out;            // 1024*256
    float* coh_out   = theta_out + 1024 * N;     // then 1024

    kuramoto_r8<<<dim3(1024 / RB), dim3(THREADS), 0, stream>>>(
        theta0, Kmat, omega, kglob, theta_out, coh_out);
}

// Round 9
// 70.767 us; speedup vs baseline: 1.0691x; 1.0691x over previous
//
#include <hip/hip_runtime.h>
#include <math.h>

// Kuramoto fp8-MFMA, round 9: EXACT REVERT to R6 (measured best, 70.9 us).
// R7 (t-major, dep-dist-2 MFMA chains) regressed +3.7us; R8 (in-prologue K
// conversion, scattered L2 reads on the critical path) regressed +4.8us.
// R6 structure: pack_k pre-dispatch (coalesced fp8 frag-packing of K into d_ws)
// + main kernel with interleaved 4-accumulator-chain GEMM (dep distance 4 >=
// MFMA latency), clean-pair LDS staging, rotation updates, 1 barrier/step.
//
// GEMM (transposed): G^T = K . S^T; A = K fp8 (VGPR-resident frags), B = staged
// sin/cos fp8. D[row=4q+r -> osc-in-tile][col=l15 -> batch].
// Staging unit u (16B) = [S(8 osc)|C(8 osc)], phys = u ^ l15 swizzle: one
// ds_read_b128 -> long2 {Bs,Bc} used directly as MFMA B-operands.
// Rotation update: small-angle poly (|d|<=0.06, err ~6e-9), no in-loop trans.
// Layouts HW-verified by R2-R8 passing. absmax floor = 1 bf16 ulp (0.015625).

typedef __attribute__((ext_vector_type(4))) float f32x4;
typedef __attribute__((ext_vector_type(2))) long long2_t;

constexpr int N       = 256;
constexpr int RB      = 16;     // batch rows per block -> 64 blocks (structural cap)
constexpr int STEPS   = 10;
constexpr int WAVES   = 8;
constexpr int THREADS = WAVES * 64;
constexpr float DT    = 0.1f;
constexpr float TWO_PI     = 6.28318530717958648f;
constexpr float INV_TWO_PI = 0.15915494309189535f;

// ---- pre-kernel: K fp32 -> frag-ordered fp8 in ws ----
// unit id = T*512 + c*64 + lane (8 bytes each): K[16T+l15][32c+8q .. +8) as fp8.
__global__ __launch_bounds__(512)
void pack_k(const float* __restrict__ Kmat, unsigned char* __restrict__ kf8)
{
    const int id   = blockIdx.x * blockDim.x + threadIdx.x;   // 0..8191
    const int T    = id >> 9;
    const int c    = (id >> 6) & 7;
    const int lane = id & 63;
    const int q    = lane >> 4, l15 = lane & 15;
    const float* src = Kmat + (size_t)(16 * T + l15) * N + 32 * c + 8 * q;
    float4 lo = *(const float4*)src;
    float4 hi = *(const float4*)(src + 4);
    int w0 = __builtin_amdgcn_cvt_pk_fp8_f32(lo.x, lo.y, 0, false);
    w0     = __builtin_amdgcn_cvt_pk_fp8_f32(lo.z, lo.w, w0, true);
    int w1 = __builtin_amdgcn_cvt_pk_fp8_f32(hi.x, hi.y, 0, false);
    w1     = __builtin_amdgcn_cvt_pk_fp8_f32(hi.z, hi.w, w1, true);
    int2 out; out.x = w0; out.y = w1;
    *(int2*)(kf8 + (size_t)id * 8) = out;
}

__global__ __launch_bounds__(THREADS, 2)
void kuramoto_r9(const float* __restrict__ theta0,
                 const unsigned char* __restrict__ kf8,
                 const float* __restrict__ omega,
                 const float* __restrict__ kglob,
                 float* __restrict__ theta_out,
                 float* __restrict__ coh_out)
{
    // [buf][row l15 * 512B]; 32 units/row of 16B = [S(8)|C(8)]; phys = u ^ l15.
    __shared__ __align__(16) unsigned char SC[2][RB * 512];
    __shared__ float redS[RB][WAVES], redC[RB][WAVES];

    const int tid  = threadIdx.x;
    const int wv   = tid >> 6;      // wave -> osc slab [32wv, 32wv+32), tiles 2wv, 2wv+1
    const int lane = tid & 63;
    const int q    = lane >> 4;
    const int l15  = lane & 15;     // batch-in-block (B-frag n / D col)
    const int b0   = blockIdx.x * RB;

    const float kgn = kglob[0] * (1.0f / 256.0f);

    // ---- K frags from pre-packed ws: kf[t][c], coalesced b64 loads ----
    long kf[2][8];
#pragma unroll
    for (int t = 0; t < 2; ++t) {
        const unsigned char* base = kf8 + (size_t)((2 * wv + t) * 512 + lane) * 8;
#pragma unroll
        for (int c = 0; c < 8; ++c)
            kf[t][c] = *(const long*)(base + (size_t)c * 512);
    }

    // ---- rotation state: 8 osc/thread (t=0,1; r=0..3 at osc 32wv+16t+4q+r) ----
    float th[8], om[8], sn[8], cs[8];
#pragma unroll
    for (int t = 0; t < 2; ++t) {
        const int ob = 32 * wv + 16 * t + 4 * q;
        float4 t4 = *(const float4*)(theta0 + (size_t)(b0 + l15) * N + ob);
        float4 o4 = *(const float4*)(omega + ob);
        th[4*t+0] = t4.x; th[4*t+1] = t4.y; th[4*t+2] = t4.z; th[4*t+3] = t4.w;
        om[4*t+0] = o4.x; om[4*t+1] = o4.y; om[4*t+2] = o4.z; om[4*t+3] = o4.w;
    }
#pragma unroll
    for (int k = 0; k < 8; ++k)
        __sincosf(th[k], &sn[k], &cs[k]);

    const int so = 4 * (q & 1);          // dword slot within unit half
    const int g0 = 4 * wv + (q >> 1);    // staging unit of tile t=0 (t adds 2)

    for (int s = 0; s < STEPS; ++s) {
        unsigned char* rowp = &SC[s & 1][l15 * 512];
        // ---- stage: pack 4 osc of S and C per tile, two b32 writes ----
#pragma unroll
        for (int t = 0; t < 2; ++t) {
            int spk = __builtin_amdgcn_cvt_pk_fp8_f32(sn[4*t+0], sn[4*t+1], 0, false);
            spk     = __builtin_amdgcn_cvt_pk_fp8_f32(sn[4*t+2], sn[4*t+3], spk, true);
            int cpk = __builtin_amdgcn_cvt_pk_fp8_f32(cs[4*t+0], cs[4*t+1], 0, false);
            cpk     = __builtin_amdgcn_cvt_pk_fp8_f32(cs[4*t+2], cs[4*t+3], cpk, true);
            const int base = (((g0 + 2 * t) ^ l15) << 4);
            *(int*)(rowp + base + so)     = spk;   // S half
            *(int*)(rowp + base + 8 + so) = cpk;   // C half
        }
        __syncthreads();   // single barrier/step; double buffer covers WAR

        // ---- GEMMs: one b128 -> {Bs,Bc}, 4 interleaved acc chains (dep dist 4) ----
        f32x4 aS[2], aC[2];
        aS[0] = (f32x4){0.f,0.f,0.f,0.f}; aS[1] = (f32x4){0.f,0.f,0.f,0.f};
        aC[0] = (f32x4){0.f,0.f,0.f,0.f}; aC[1] = (f32x4){0.f,0.f,0.f,0.f};
#pragma unroll
        for (int c = 0; c < 8; ++c) {
            long2_t v = *(const long2_t*)(rowp + ((((4 * c + q) ^ l15)) << 4));
            aS[0] = __builtin_amdgcn_mfma_f32_16x16x32_fp8_fp8(kf[0][c], v.x, aS[0], 0, 0, 0);
            aC[0] = __builtin_amdgcn_mfma_f32_16x16x32_fp8_fp8(kf[0][c], v.y, aC[0], 0, 0, 0);
            aS[1] = __builtin_amdgcn_mfma_f32_16x16x32_fp8_fp8(kf[1][c], v.x, aS[1], 0, 0, 0);
            aC[1] = __builtin_amdgcn_mfma_f32_16x16x32_fp8_fp8(kf[1][c], v.y, aC[1], 0, 0, 0);
        }

        // ---- rotation update (no transcendentals) ----
#pragma unroll
        for (int t = 0; t < 2; ++t)
#pragma unroll
            for (int r = 0; r < 4; ++r) {
                const int k = 4 * t + r;
                float coup = cs[k] * aS[t][r] - sn[k] * aC[t][r];
                float d  = DT * fmaf(kgn, coup, om[k]);
                float d2 = d * d;
                float sd = d * fmaf(d2, -1.0f / 6.0f, 1.0f);              // sin(d)
                float cd = fmaf(d2, fmaf(d2, 1.0f / 24.0f, -0.5f), 1.0f); // cos(d)
                float s2 = fmaf(sn[k], cd,  cs[k] * sd);
                float c2 = fmaf(cs[k], cd, -sn[k] * sd);
                sn[k] = s2; cs[k] = c2; th[k] += d;
            }
    }

    // ---- epilogue: wrap, float4 stores, coherence from live (s,c) ----
    float ps = 0.f, pc = 0.f;
#pragma unroll
    for (int t = 0; t < 2; ++t) {
        const int ob = 32 * wv + 16 * t + 4 * q;
        float4 outv;
        outv.x = fmaf(-TWO_PI, rintf(th[4*t+0] * INV_TWO_PI), th[4*t+0]);
        outv.y = fmaf(-TWO_PI, rintf(th[4*t+1] * INV_TWO_PI), th[4*t+1]);
        outv.z = fmaf(-TWO_PI, rintf(th[4*t+2] * INV_TWO_PI), th[4*t+2]);
        outv.w = fmaf(-TWO_PI, rintf(th[4*t+3] * INV_TWO_PI), th[4*t+3]);
        *(float4*)(theta_out + (size_t)(b0 + l15) * N + ob) = outv;
#pragma unroll
        for (int r = 0; r < 4; ++r) { ps += sn[4*t+r]; pc += cs[4*t+r]; }
    }
    ps += __shfl_xor(ps, 16, 64);  pc += __shfl_xor(pc, 16, 64);
    ps += __shfl_xor(ps, 32, 64);  pc += __shfl_xor(pc, 32, 64);
    if (q == 0) { redS[l15][wv] = ps; redC[l15][wv] = pc; }
    __syncthreads();
    if (tid < RB) {
        float S = 0.f, C = 0.f;
#pragma unroll
        for (int k = 0; k < WAVES; ++k) { S += redS[tid][k]; C += redC[tid][k]; }
        float sm = S * (1.0f / 256.0f);
        float cm = C * (1.0f / 256.0f);
        coh_out[b0 + tid] = sqrtf(sm * sm + cm * cm);
    }
}

extern "C" void kernel_launch(void* const* d_in, const int* in_sizes, int n_in,
                              void* d_out, int out_size, void* d_ws, size_t ws_size,
                              hipStream_t stream) {
    const float* theta0 = (const float*)d_in[0];
    const float* Kmat   = (const float*)d_in[1];
    const float* omega  = (const float*)d_in[2];
    const float* kglob  = (const float*)d_in[3];

    unsigned char* kf8 = (unsigned char*)d_ws;   // 64 KB fp8 frag-ordered K

    float* theta_out = (float*)d_out;            // 1024*256
    float* coh_out   = theta_out + 1024 * N;     // then 1024

    pack_k<<<dim3(16), dim3(512), 0, stream>>>(Kmat, kf8);
    kuramoto_r9<<<dim3(1024 / RB), dim3(THREADS), 0, stream>>>(
        theta0, kf8, omega, kglob, theta_out, coh_out);
}